// Round 1
// baseline (569.364 us; speedup 1.0000x reference)
//
#include <hip/hip_runtime.h>
#include <math.h>

#define Vv   50000
#define EMB  128
#define Hh   256
#define TKk  400
#define Bb   128
#define OOVn 10
#define N2n  512
#define VOo  50010   // V + OOV

__device__ __forceinline__ float sigf(float x) { return 1.f / (1.f + __expf(-x)); }
__device__ __forceinline__ float tanh_fast(float x) {
    x = fminf(15.f, fmaxf(-15.f, x));
    float e = __expf(2.f * x);
    return (e - 1.f) / (e + 1.f);
}

// ---------------------------------------------------------------------------
// K1: embedding gather -> x = [c_t_1, emb] @ Wx^T + bx -> LSTM cell -> dec_fea
// one block per batch row, 512 threads
// ---------------------------------------------------------------------------
__global__ __launch_bounds__(512) void k_cell(
    const int* __restrict__ y, const float* __restrict__ h0g,
    const float* __restrict__ c0g, const float* __restrict__ ct1,
    const float* __restrict__ emb, const float* __restrict__ Wx,
    const float* __restrict__ bx, const float* __restrict__ wih,
    const float* __restrict__ bih, const float* __restrict__ whh,
    const float* __restrict__ bhh, const float* __restrict__ Wp,
    const float* __restrict__ bp,
    float* __restrict__ h1o, float* __restrict__ c1o,
    float* __restrict__ dfw, float* __restrict__ xw)
{
    int b = blockIdx.x, tid = threadIdx.x;
    __shared__ float cr[N2n], ye[EMB], h0[Hh], c0[Hh], xs[EMB], gs[1024], sh[N2n];

    cr[tid] = ct1[b * N2n + tid];
    if (tid < EMB) { int yy = y[b]; ye[tid] = emb[(size_t)yy * EMB + tid]; }
    if (tid < Hh)  { h0[tid] = h0g[b * Hh + tid]; c0[tid] = c0g[b * Hh + tid]; }
    __syncthreads();

    // x = concat(c_t_1[512], y_embd[128]) @ Wx^T + bx   -> [128]
    if (tid < EMB) {
        const float4* w4 = (const float4*)(Wx + (size_t)tid * 640);
        float a = bx[tid];
        #pragma unroll 4
        for (int k = 0; k < 128; k++) {
            float4 wv = w4[k];
            a += cr[4*k]*wv.x + cr[4*k+1]*wv.y + cr[4*k+2]*wv.z + cr[4*k+3]*wv.w;
        }
        #pragma unroll 4
        for (int k = 0; k < 32; k++) {
            float4 wv = w4[128 + k];
            a += ye[4*k]*wv.x + ye[4*k+1]*wv.y + ye[4*k+2]*wv.z + ye[4*k+3]*wv.w;
        }
        xs[tid] = a;
        xw[b * EMB + tid] = a;
    }
    __syncthreads();

    // gates = x @ w_ih^T + b_ih + h0 @ w_hh^T + b_hh  -> [1024]
    for (int j = tid; j < 1024; j += 512) {
        const float4* wi = (const float4*)(wih + (size_t)j * EMB);
        const float4* wh = (const float4*)(whh + (size_t)j * Hh);
        float a = bih[j] + bhh[j];
        #pragma unroll 4
        for (int k = 0; k < 32; k++) {
            float4 wv = wi[k];
            a += xs[4*k]*wv.x + xs[4*k+1]*wv.y + xs[4*k+2]*wv.z + xs[4*k+3]*wv.w;
        }
        #pragma unroll 4
        for (int k = 0; k < 64; k++) {
            float4 wv = wh[k];
            a += h0[4*k]*wv.x + h0[4*k+1]*wv.y + h0[4*k+2]*wv.z + h0[4*k+3]*wv.w;
        }
        gs[j] = a;
    }
    __syncthreads();

    // LSTM cell (torch gate order i,f,g,o)
    if (tid < Hh) {
        float ig = sigf(gs[tid]);
        float fg = sigf(gs[Hh + tid]);
        float gg = tanh_fast(gs[2 * Hh + tid]);
        float og = sigf(gs[3 * Hh + tid]);
        float c1 = fg * c0[tid] + ig * gg;
        float h1 = og * tanh_fast(c1);
        h1o[b * Hh + tid] = h1;
        c1o[b * Hh + tid] = c1;
        sh[tid] = h1;
        sh[Hh + tid] = c1;
    }
    __syncthreads();

    // dec_fea = s_t_hat @ Wp^T + bp  -> [512]
    {
        const float4* w4 = (const float4*)(Wp + (size_t)tid * N2n);
        float a = bp[tid];
        #pragma unroll 4
        for (int k = 0; k < 128; k++) {
            float4 wv = w4[k];
            a += sh[4*k]*wv.x + sh[4*k+1]*wv.y + sh[4*k+2]*wv.z + sh[4*k+3]*wv.w;
        }
        dfw[b * N2n + tid] = a;
    }
}

// ---------------------------------------------------------------------------
// K2: scores[b,t] = sum_n tanh(ef[b,t,n] + df[b,n] + cov[b,t]*Wc[n]) * v[n]
// one wave per (b,t); block = 4 waves
// ---------------------------------------------------------------------------
__global__ __launch_bounds__(256) void k_scores(
    const float* __restrict__ ef, const float* __restrict__ df,
    const float* __restrict__ cov, const float* __restrict__ Wc,
    const float* __restrict__ vw, float* __restrict__ sc)
{
    int w = threadIdx.x >> 6, lane = threadIdx.x & 63;
    int idx = blockIdx.x * 4 + w;          // b*TK + t
    int b = idx / TKk;
    const float* e = ef + (size_t)idx * N2n;
    const float* d = df + (size_t)b * N2n;
    float cv = cov[idx];
    float acc = 0.f;
    #pragma unroll
    for (int i = 0; i < 2; i++) {
        int n0 = lane * 4 + i * 256;
        float4 ev = *(const float4*)(e + n0);
        float4 dv = *(const float4*)(d + n0);
        float4 wc = *(const float4*)(Wc + n0);
        float4 vv = *(const float4*)(vw + n0);
        acc += tanh_fast(ev.x + dv.x + cv * wc.x) * vv.x;
        acc += tanh_fast(ev.y + dv.y + cv * wc.y) * vv.y;
        acc += tanh_fast(ev.z + dv.z + cv * wc.z) * vv.z;
        acc += tanh_fast(ev.w + dv.w + cv * wc.w) * vv.w;
    }
    for (int off = 32; off; off >>= 1) acc += __shfl_down(acc, off);
    if (lane == 0) sc[idx] = acc;
}

// ---------------------------------------------------------------------------
// K3: masked softmax over TK + renorm + coverage update. one block per b.
// ---------------------------------------------------------------------------
__global__ __launch_bounds__(512) void k_attn(
    const float* __restrict__ sc, const float* __restrict__ mask,
    const float* __restrict__ covi, float* __restrict__ attn,
    float* __restrict__ covo)
{
    int b = blockIdx.x, tid = threadIdx.x;
    __shared__ float red[8];
    __shared__ float bc;
    float s = (tid < TKk) ? sc[b * TKk + tid] : -3.4e38f;
    float m = s;
    for (int off = 32; off; off >>= 1) m = fmaxf(m, __shfl_down(m, off));
    if ((tid & 63) == 0) red[tid >> 6] = m;
    __syncthreads();
    if (tid == 0) {
        float t = red[0];
        for (int i = 1; i < 8; i++) t = fmaxf(t, red[i]);
        bc = t;
    }
    __syncthreads();
    float M = bc;
    float w = (tid < TKk) ? __expf(s - M) * mask[b * TKk + tid] : 0.f;
    float ss = w;
    for (int off = 32; off; off >>= 1) ss += __shfl_down(ss, off);
    if ((tid & 63) == 0) red[tid >> 6] = ss;
    __syncthreads();
    if (tid == 0) {
        float t = 0.f;
        for (int i = 0; i < 8; i++) t += red[i];
        bc = t;
    }
    __syncthreads();
    float a = w / bc;
    if (tid < TKk) {
        attn[b * TKk + tid] = a;
        covo[b * TKk + tid] = covi[b * TKk + tid] + a;
    }
}

// ---------------------------------------------------------------------------
// K4: context partials: part[b,s,n] = sum_{t in chunk s} attn[b,t]*eo[b,t,n]
// grid = B*4 blocks, 512 threads (n)
// ---------------------------------------------------------------------------
__global__ __launch_bounds__(512) void k_ctx(
    const float* __restrict__ attn, const float* __restrict__ eo,
    float* __restrict__ part)
{
    int bs = blockIdx.x;
    int b = bs >> 2, s = bs & 3;
    int n = threadIdx.x;
    __shared__ float av[100];
    if (n < 100) av[n] = attn[b * TKk + s * 100 + n];
    __syncthreads();
    const float* p = eo + ((size_t)b * TKk + s * 100) * N2n + n;
    float acc = 0.f;
    #pragma unroll 4
    for (int t = 0; t < 100; t++) acc += av[t] * p[(size_t)t * N2n];
    part[(size_t)bs * N2n + n] = acc;
}

// ---------------------------------------------------------------------------
// K5: c_t reduce + p_gen + output = [h1,c_t] @ W1^T + b1. one block per b.
// ---------------------------------------------------------------------------
__global__ __launch_bounds__(512) void k_epi(
    const float* __restrict__ part, const float* __restrict__ h1g,
    const float* __restrict__ c1g, const float* __restrict__ xw,
    const float* __restrict__ Wpg, const float* __restrict__ bpg,
    const float* __restrict__ W1, const float* __restrict__ b1,
    float* __restrict__ cto, float* __restrict__ pgo, float* __restrict__ ov)
{
    int b = blockIdx.x, tid = threadIdx.x;
    __shared__ float ct[N2n], h1s[Hh], c1s[Hh], xs[EMB];
    __shared__ float red[8];
    {
        float a = part[((size_t)b * 4 + 0) * N2n + tid]
                + part[((size_t)b * 4 + 1) * N2n + tid]
                + part[((size_t)b * 4 + 2) * N2n + tid]
                + part[((size_t)b * 4 + 3) * N2n + tid];
        ct[tid] = a;
        cto[b * N2n + tid] = a;
    }
    if (tid < Hh) { h1s[tid] = h1g[b * Hh + tid]; c1s[tid] = c1g[b * Hh + tid]; }
    if (tid < EMB) xs[tid] = xw[b * EMB + tid];
    __syncthreads();

    // p_gen = sigmoid(Wpg . [c_t(512), h1(256), c1(256), x(128)] + bpg)
    float pa = 0.f;
    for (int k = tid; k < 1152; k += 512) {
        float vv = (k < 512) ? ct[k] : (k < 768) ? h1s[k - 512]
                 : (k < 1024) ? c1s[k - 768] : xs[k - 1024];
        pa += vv * Wpg[k];
    }
    for (int off = 32; off; off >>= 1) pa += __shfl_down(pa, off);
    if ((tid & 63) == 0) red[tid >> 6] = pa;
    __syncthreads();
    if (tid == 0) {
        float t = 0.f;
        for (int i = 0; i < 8; i++) t += red[i];
        pgo[b] = sigf(t + bpg[0]);
    }

    // output[j] = b1[j] + h1 . W1[j,0:256] + c_t . W1[j,256:768]
    if (tid < Hh) {
        const float4* w4 = (const float4*)(W1 + (size_t)tid * 768);
        float acc = b1[tid];
        #pragma unroll 4
        for (int k = 0; k < 64; k++) {
            float4 wv = w4[k];
            acc += h1s[4*k]*wv.x + h1s[4*k+1]*wv.y + h1s[4*k+2]*wv.z + h1s[4*k+3]*wv.w;
        }
        #pragma unroll 4
        for (int k = 0; k < 128; k++) {
            float4 wv = w4[64 + k];
            acc += ct[4*k]*wv.x + ct[4*k+1]*wv.y + ct[4*k+2]*wv.z + ct[4*k+3]*wv.w;
        }
        ov[b * Hh + tid] = acc;
    }
}

// ---------------------------------------------------------------------------
// K6: logits = output[128,256] @ W2^T[256,V] + b2, written into final_dist
// rows (stride VO). Tiled fp32 GEMM: block = 256 thr, tile M=128 x N=128,
// micro 8x8, Kc=16.
// ---------------------------------------------------------------------------
__global__ __launch_bounds__(256) void k_gemm(
    const float* __restrict__ Aw, const float* __restrict__ W2,
    const float* __restrict__ b2, float* __restrict__ fd)
{
    __shared__ float As[16][128];
    __shared__ float Bs[16][128];
    int tid = threadIdx.x;
    int tx = tid & 15, ty = tid >> 4;
    int v0 = blockIdx.x * 128;
    int lm = tid & 127;     // row (m or v) for staging loads
    int lh = tid >> 7;      // which k-half (0/1)

    float acc[8][8];
    #pragma unroll
    for (int i = 0; i < 8; i++)
        #pragma unroll
        for (int j = 0; j < 8; j++) acc[i][j] = 0.f;

    for (int kt = 0; kt < 256; kt += 16) {
        float4 a0 = *(const float4*)(Aw + (size_t)lm * 256 + kt + lh * 8);
        float4 a1 = *(const float4*)(Aw + (size_t)lm * 256 + kt + lh * 8 + 4);
        int vv = v0 + lm;
        float4 b0 = make_float4(0.f, 0.f, 0.f, 0.f), b1v = b0;
        if (vv < Vv) {
            b0  = *(const float4*)(W2 + (size_t)vv * 256 + kt + lh * 8);
            b1v = *(const float4*)(W2 + (size_t)vv * 256 + kt + lh * 8 + 4);
        }
        __syncthreads();
        As[lh*8+0][lm] = a0.x; As[lh*8+1][lm] = a0.y; As[lh*8+2][lm] = a0.z; As[lh*8+3][lm] = a0.w;
        As[lh*8+4][lm] = a1.x; As[lh*8+5][lm] = a1.y; As[lh*8+6][lm] = a1.z; As[lh*8+7][lm] = a1.w;
        Bs[lh*8+0][lm] = b0.x; Bs[lh*8+1][lm] = b0.y; Bs[lh*8+2][lm] = b0.z; Bs[lh*8+3][lm] = b0.w;
        Bs[lh*8+4][lm] = b1v.x; Bs[lh*8+5][lm] = b1v.y; Bs[lh*8+6][lm] = b1v.z; Bs[lh*8+7][lm] = b1v.w;
        __syncthreads();
        #pragma unroll
        for (int k = 0; k < 16; k++) {
            float4 av0 = *(const float4*)&As[k][ty * 8];
            float4 av1 = *(const float4*)&As[k][ty * 8 + 4];
            float4 bv0 = *(const float4*)&Bs[k][tx * 8];
            float4 bv1 = *(const float4*)&Bs[k][tx * 8 + 4];
            float am[8] = {av0.x, av0.y, av0.z, av0.w, av1.x, av1.y, av1.z, av1.w};
            float bn[8] = {bv0.x, bv0.y, bv0.z, bv0.w, bv1.x, bv1.y, bv1.z, bv1.w};
            #pragma unroll
            for (int i = 0; i < 8; i++)
                #pragma unroll
                for (int j = 0; j < 8; j++) acc[i][j] += am[i] * bn[j];
        }
    }
    #pragma unroll
    for (int i = 0; i < 8; i++) {
        int m = ty * 8 + i;
        #pragma unroll
        for (int j = 0; j < 8; j++) {
            int v = v0 + tx * 8 + j;
            if (v < Vv) fd[(size_t)m * VOo + v] = acc[i][j] + b2[v];
        }
    }
}

// ---------------------------------------------------------------------------
// K7: in-place vocab softmax * p_gen over final_dist rows + OOV tail copy
// one block per b, 1024 threads
// ---------------------------------------------------------------------------
__global__ __launch_bounds__(1024) void k_vsoft(
    const float* __restrict__ pgen, const float* __restrict__ extra,
    float* __restrict__ fd)
{
    int b = blockIdx.x, tid = threadIdx.x;
    __shared__ float red[16];
    __shared__ float bc;
    float* l = fd + (size_t)b * VOo;
    float m = -3.4e38f;
    for (int v = tid; v < Vv; v += 1024) m = fmaxf(m, l[v]);
    for (int off = 32; off; off >>= 1) m = fmaxf(m, __shfl_down(m, off));
    if ((tid & 63) == 0) red[tid >> 6] = m;
    __syncthreads();
    if (tid == 0) {
        float t = red[0];
        for (int i = 1; i < 16; i++) t = fmaxf(t, red[i]);
        bc = t;
    }
    __syncthreads();
    float M = bc;
    float s = 0.f;
    for (int v = tid; v < Vv; v += 1024) s += __expf(l[v] - M);
    for (int off = 32; off; off >>= 1) s += __shfl_down(s, off);
    if ((tid & 63) == 0) red[tid >> 6] = s;
    __syncthreads();
    if (tid == 0) {
        float t = 0.f;
        for (int i = 0; i < 16; i++) t += red[i];
        bc = t;
    }
    __syncthreads();
    float scale = pgen[b] / bc;
    for (int v = tid; v < Vv; v += 1024) l[v] = __expf(l[v] - M) * scale;
    if (tid < OOVn) l[Vv + tid] = extra[b * OOVn + tid];
}

// ---------------------------------------------------------------------------
// K8: pointer scatter-add: fd[b, ebev[b,t]] += (1-p_gen[b]) * attn[b,t]
// ---------------------------------------------------------------------------
__global__ __launch_bounds__(256) void k_scatter(
    const int* __restrict__ ebev, const float* __restrict__ attn,
    const float* __restrict__ pgen, float* __restrict__ fd)
{
    int gid = blockIdx.x * 256 + threadIdx.x;
    if (gid >= Bb * TKk) return;
    int b = gid / TKk;
    float w = (1.f - pgen[b]) * attn[gid];
    atomicAdd(fd + (size_t)b * VOo + ebev[gid], w);
}

// ---------------------------------------------------------------------------
extern "C" void kernel_launch(void* const* d_in, const int* in_sizes, int n_in,
                              void* d_out, int out_size, void* d_ws, size_t ws_size,
                              hipStream_t stream)
{
    (void)in_sizes; (void)n_in; (void)out_size; (void)ws_size;

    const int*   y    = (const int*)d_in[0];
    const float* h0   = (const float*)d_in[1];
    const float* c0   = (const float*)d_in[2];
    const float* eo   = (const float*)d_in[3];
    const float* ef   = (const float*)d_in[4];
    const float* mask = (const float*)d_in[5];
    const float* ct1  = (const float*)d_in[6];
    const float* xz   = (const float*)d_in[7];
    const int*   ebev = (const int*)d_in[8];
    const float* cov  = (const float*)d_in[9];
    // d_in[10] = step (unused: coverage path taken unconditionally)
    const float* emb  = (const float*)d_in[11];
    const float* Wx   = (const float*)d_in[12];
    const float* bx   = (const float*)d_in[13];
    const float* wih  = (const float*)d_in[14];
    const float* bih  = (const float*)d_in[15];
    const float* whh  = (const float*)d_in[16];
    const float* bhh  = (const float*)d_in[17];
    const float* Wp   = (const float*)d_in[18];
    const float* bp   = (const float*)d_in[19];
    const float* vw   = (const float*)d_in[20];
    const float* Wc   = (const float*)d_in[21];
    const float* Wpg  = (const float*)d_in[22];
    const float* bpg  = (const float*)d_in[23];
    const float* W1   = (const float*)d_in[24];
    const float* b1   = (const float*)d_in[25];
    const float* W2   = (const float*)d_in[26];
    const float* b2   = (const float*)d_in[27];

    float* out   = (float*)d_out;
    float* fd    = out;                              // [B, VO]
    float* h1o   = out + (size_t)Bb * VOo;           // [B, H]
    float* c1o   = h1o + (size_t)Bb * Hh;            // [B, H]
    float* cto   = c1o + (size_t)Bb * Hh;            // [B, N2]
    float* attno = cto + (size_t)Bb * N2n;           // [B, TK]
    float* pgo   = attno + (size_t)Bb * TKk;         // [B]
    float* covo  = pgo + Bb;                         // [B, TK]

    float* ws  = (float*)d_ws;
    float* xw  = ws;                                 // [B,128]
    float* dfw = xw + (size_t)Bb * EMB;              // [B,512]
    float* scw = dfw + (size_t)Bb * N2n;             // [B,400]
    float* prt = scw + (size_t)Bb * TKk;             // [B,4,512]
    float* ov  = prt + (size_t)Bb * 4 * N2n;         // [B,256]

    k_cell<<<Bb, 512, 0, stream>>>(y, h0, c0, ct1, emb, Wx, bx, wih, bih,
                                   whh, bhh, Wp, bp, h1o, c1o, dfw, xw);
    k_scores<<<Bb * TKk / 4, 256, 0, stream>>>(ef, dfw, cov, Wc, vw, scw);
    k_attn<<<Bb, 512, 0, stream>>>(scw, mask, cov, attno, covo);
    k_ctx<<<Bb * 4, 512, 0, stream>>>(attno, eo, prt);
    k_epi<<<Bb, 512, 0, stream>>>(prt, h1o, c1o, xw, Wpg, bpg, W1, b1,
                                  cto, pgo, ov);
    k_gemm<<<(Vv + 127) / 128, 256, 0, stream>>>(ov, W2, b2, fd);
    k_vsoft<<<Bb, 1024, 0, stream>>>(pgo, xz, fd);
    k_scatter<<<(Bb * TKk + 255) / 256, 256, 0, stream>>>(ebev, attno, pgo, fd);
}